// Round 1
// baseline (3792.799 us; speedup 1.0000x reference)
//
#include <hip/hip_runtime.h>
#include <math.h>

#define BS   1024
#define H    10
#define S    62      // node == region
#define D    65
#define SP   63      // padded stride for attention matrices (63 % 32 = 31 -> conflict-free)
#define NT   512
#define FUSED_SIZE (BS * H * 2 * S * D)   // 82,534,400

// ---------------------------------------------------------------------------
// Kernel 1: gate g[b, :] = sigmoid(concat(mean_n Fn[b], mean_r Fr[b]) @ Wg.T + bg)
// ---------------------------------------------------------------------------
__global__ __launch_bounds__(192) void gate_kernel(
    const float* __restrict__ Fn, const float* __restrict__ Fr,
    const float* __restrict__ Wg, const float* __restrict__ bg,
    float* __restrict__ g_out)
{
    int b = blockIdx.x;
    int t = threadIdx.x;
    __shared__ float m[2 * D];

    if (t < 2 * D) {
        const float* src = (t < D) ? (Fn + (size_t)b * S * D + t)
                                   : (Fr + (size_t)b * S * D + (t - D));
        float s = 0.f;
        for (int r = 0; r < S; ++r) s += src[(size_t)r * D];
        m[t] = s * (1.0f / (float)S);
    }
    __syncthreads();
    if (t < D) {
        const float* w = Wg + (size_t)t * (2 * D);
        float a0 = 0.f, a1 = 0.f, a2 = 0.f, a3 = 0.f;
        int k = 0;
        for (; k + 3 < 2 * D; k += 4) {
            a0 += m[k] * w[k];     a1 += m[k + 1] * w[k + 1];
            a2 += m[k + 2] * w[k + 2]; a3 += m[k + 3] * w[k + 3];
        }
        for (; k < 2 * D; ++k) a0 += m[k] * w[k];
        float o = bg[t] + ((a0 + a1) + (a2 + a3));
        g_out[(size_t)b * D + t] = 1.0f / (1.0f + __expf(-o));
    }
}

// ---------------------------------------------------------------------------
// Kernel 2: per-(b,h) fused attention
// ---------------------------------------------------------------------------
__device__ __forceinline__ void project(const float (*__restrict__ src)[D],
                                        float (*__restrict__ dst)[D],
                                        const float* __restrict__ W,
                                        const float* __restrict__ bias,
                                        int h, int tid)
{
    // dst[n][j] = bias[h*D+j] + sum_d src[n][d] * W[(h*D+j)*D + d]
    // j-major work split: lanes in a wave mostly share j -> W reads are broadcast,
    // src reads walk consecutive banks (stride 65, odd).
    for (int idx = tid; idx < S * D; idx += NT) {
        int j = idx / S;
        int n = idx - j * S;
        const float* w = W + (size_t)(h * D + j) * D;
        const float* x = src[n];
        float a0 = 0.f, a1 = 0.f, a2 = 0.f, a3 = 0.f;
        int d = 0;
        #pragma unroll
        for (; d + 3 < D; d += 4) {
            a0 += x[d] * w[d];         a1 += x[d + 1] * w[d + 1];
            a2 += x[d + 2] * w[d + 2]; a3 += x[d + 3] * w[d + 3];
        }
        for (; d < D; ++d) a0 += x[d] * w[d];
        dst[n][j] = bias[h * D + j] + ((a0 + a1) + (a2 + a3));
    }
}

__device__ __forceinline__ void qk_softmax(const float (*__restrict__ Q)[D],
                                           const float (*__restrict__ K)[D],
                                           float (*__restrict__ A)[SP],
                                           float scale, int tid)
{
    // logits
    for (int idx = tid; idx < S * S; idx += NT) {
        int n = idx / S, r = idx - n * S;
        const float* q = Q[n];
        const float* k = K[r];
        float a0 = 0.f, a1 = 0.f, a2 = 0.f, a3 = 0.f;
        int d = 0;
        #pragma unroll
        for (; d + 3 < D; d += 4) {
            a0 += q[d] * k[d];         a1 += q[d + 1] * k[d + 1];
            a2 += q[d + 2] * k[d + 2]; a3 += q[d + 3] * k[d + 3];
        }
        for (; d < D; ++d) a0 += q[d] * k[d];
        A[n][r] = scale * ((a0 + a1) + (a2 + a3));
    }
    __syncthreads();
    // row softmax: 8 lanes per row (62 rows -> threads 0..495)
    if (tid < S * 8) {
        int row = tid >> 3, u = tid & 7;
        float mx = -INFINITY;
        for (int e = u; e < S; e += 8) mx = fmaxf(mx, A[row][e]);
        mx = fmaxf(mx, __shfl_xor(mx, 1));
        mx = fmaxf(mx, __shfl_xor(mx, 2));
        mx = fmaxf(mx, __shfl_xor(mx, 4));
        float sm = 0.f;
        for (int e = u; e < S; e += 8) {
            float v = __expf(A[row][e] - mx);
            A[row][e] = v;
            sm += v;
        }
        sm += __shfl_xor(sm, 1);
        sm += __shfl_xor(sm, 2);
        sm += __shfl_xor(sm, 4);
        float inv = 1.0f / sm;
        for (int e = u; e < S; e += 8) A[row][e] *= inv;
    }
}

__global__ __launch_bounds__(NT) void attn_kernel(
    const float* __restrict__ Fn, const float* __restrict__ Fr,
    const float* __restrict__ Wq1, const float* __restrict__ bq1,
    const float* __restrict__ Wk1, const float* __restrict__ bk1,
    const float* __restrict__ Wq2, const float* __restrict__ bq2,
    const float* __restrict__ Wk2, const float* __restrict__ bk2,
    const float* __restrict__ g, float* __restrict__ out,
    float* __restrict__ orth_accum)
{
    const int blk = blockIdx.x;
    const int b = blk / H;
    const int h = blk % H;
    const int tid = threadIdx.x;
    const float scale = 0.12403473458920847f; // 1/sqrt(65)

    __shared__ float sFn[S][D];
    __shared__ float sFr[S][D];
    __shared__ float sQ[S][D];
    __shared__ float sK[S][D];
    __shared__ float sA1[S][SP];
    __shared__ float sA2[S][SP];
    __shared__ float sg[D];
    __shared__ float sred[NT / 64];

    // ---- load Fn[b], Fr[b], g[b] ----
    const size_t fb = (size_t)b * S * D;
    for (int i = tid; i < S * D; i += NT) {
        (&sFn[0][0])[i] = Fn[fb + i];
        (&sFr[0][0])[i] = Fr[fb + i];
    }
    for (int i = tid; i < D; i += NT) sg[i] = g[(size_t)b * D + i];
    __syncthreads();

    // ---- r2n attention: Q from Fn (Wq1), K from Fr (Wk1) ----
    project(sFn, sQ, Wq1, bq1, h, tid);
    project(sFr, sK, Wk1, bk1, h, tid);
    __syncthreads();
    qk_softmax(sQ, sK, sA1, scale, tid);
    __syncthreads();

    // ---- n2r attention: Q from Fr (Wq2), K from Fn (Wk2); reuse sQ/sK ----
    project(sFr, sQ, Wq2, bq2, h, tid);
    project(sFn, sK, Wk2, bk2, h, tid);
    __syncthreads();
    qk_softmax(sQ, sK, sA2, scale, tid);
    __syncthreads();

    // ---- C = A1 @ A2^T, orth partial ----
    float local = 0.f;
    for (int idx = tid; idx < S * S; idx += NT) {
        int i = idx / S, j = idx - i * S;
        const float* x = sA1[i];
        const float* y = sA2[j];
        float a0 = 0.f, a1 = 0.f, a2 = 0.f, a3 = 0.f;
        int k = 0;
        #pragma unroll
        for (; k + 3 < S; k += 4) {
            a0 += x[k] * y[k];         a1 += x[k + 1] * y[k + 1];
            a2 += x[k + 2] * y[k + 2]; a3 += x[k + 3] * y[k + 3];
        }
        for (; k < S; ++k) a0 += x[k] * y[k];
        float c = (a0 + a1) + (a2 + a3) - (i == j ? 1.0f : 0.0f);
        local += c * c;
    }
    // block reduce
    for (int o = 32; o; o >>= 1) local += __shfl_down(local, o);
    int wave = tid >> 6, lane = tid & 63;
    if (lane == 0) sred[wave] = local;
    __syncthreads();
    if (tid == 0) {
        float tot = 0.f;
        for (int wv = 0; wv < NT / 64; ++wv) tot += sred[wv];
        atomicAdd(orth_accum, sqrtf(tot) * (1.0f / (float)(BS * H)));
    }

    // ---- outputs: out_n = g * (A1 @ Fr), out_r = (1-g) * (A2 @ Fn) ----
    const size_t ob = (size_t)(b * H + h) * (2 * S) * D;
    for (int idx = tid; idx < S * D; idx += NT) {
        int n = idx / D, dd = idx - n * D;
        const float* a = sA1[n];
        float a0 = 0.f, a1 = 0.f, a2 = 0.f, a3 = 0.f;
        int r = 0;
        #pragma unroll
        for (; r + 3 < S; r += 4) {
            a0 += a[r] * sFr[r][dd];         a1 += a[r + 1] * sFr[r + 1][dd];
            a2 += a[r + 2] * sFr[r + 2][dd]; a3 += a[r + 3] * sFr[r + 3][dd];
        }
        for (; r < S; ++r) a0 += a[r] * sFr[r][dd];
        out[ob + idx] = sg[dd] * ((a0 + a1) + (a2 + a3));
    }
    for (int idx = tid; idx < S * D; idx += NT) {
        int rr = idx / D, dd = idx - rr * D;
        const float* a = sA2[rr];
        float a0 = 0.f, a1 = 0.f, a2 = 0.f, a3 = 0.f;
        int n = 0;
        #pragma unroll
        for (; n + 3 < S; n += 4) {
            a0 += a[n] * sFn[n][dd];         a1 += a[n + 1] * sFn[n + 1][dd];
            a2 += a[n + 2] * sFn[n + 2][dd]; a3 += a[n + 3] * sFn[n + 3][dd];
        }
        for (; n < S; ++n) a0 += a[n] * sFn[n][dd];
        out[ob + (size_t)S * D + idx] = (1.0f - sg[dd]) * ((a0 + a1) + (a2 + a3));
    }
}

// ---------------------------------------------------------------------------
extern "C" void kernel_launch(void* const* d_in, const int* in_sizes, int n_in,
                              void* d_out, int out_size, void* d_ws, size_t ws_size,
                              hipStream_t stream)
{
    const float* Fn  = (const float*)d_in[0];
    const float* Fr  = (const float*)d_in[1];
    const float* Wq1 = (const float*)d_in[2];
    const float* bq1 = (const float*)d_in[3];
    const float* Wk1 = (const float*)d_in[4];
    const float* bk1 = (const float*)d_in[5];
    const float* Wq2 = (const float*)d_in[6];
    const float* bq2 = (const float*)d_in[7];
    const float* Wk2 = (const float*)d_in[8];
    const float* bk2 = (const float*)d_in[9];
    const float* Wg  = (const float*)d_in[10];
    const float* bg  = (const float*)d_in[11];

    float* out  = (float*)d_out;
    float* g_ws = (float*)d_ws;   // 1024*65 floats

    // zero the orth-loss accumulator (d_out is poisoned 0xAA before every call)
    hipMemsetAsync(out + FUSED_SIZE, 0, sizeof(float), stream);

    gate_kernel<<<BS, 192, 0, stream>>>(Fn, Fr, Wg, bg, g_ws);
    attn_kernel<<<BS * H, NT, 0, stream>>>(Fn, Fr, Wq1, bq1, Wk1, bk1,
                                           Wq2, bq2, Wk2, bk2,
                                           g_ws, out, out + FUSED_SIZE);
}

// Round 3
// 829.563 us; speedup vs baseline: 4.5720x; 4.5720x over previous
//
#include <hip/hip_runtime.h>
#include <math.h>

#define BS   1024
#define H    10
#define S    62      // node == region
#define D    65
#define NT   512
#define FUSED_SIZE (BS * H * 2 * S * D)   // 82,534,400

typedef __bf16 bf16x8 __attribute__((ext_vector_type(8)));
typedef float  f32x4  __attribute__((ext_vector_type(4)));
typedef unsigned short u16x8 __attribute__((ext_vector_type(8)));

// f32 -> bf16 round-to-nearest-even
__device__ __forceinline__ unsigned short f2bf(float f) {
    unsigned int u = __float_as_uint(f);
    u += 0x7FFFu + ((u >> 16) & 1u);
    return (unsigned short)(u >> 16);
}

__device__ __forceinline__ bf16x8 ldfrag(const unsigned short* p) {
    u16x8 r = *(const u16x8*)p;          // ds_read_b128 (16B aligned by construction)
    return __builtin_bit_cast(bf16x8, r);
}

#define MFMA16(acc, a, b) acc = __builtin_amdgcn_mfma_f32_16x16x32_bf16(a, b, acc, 0, 0, 0)

// ---------------------------------------------------------------------------
// Kernel 1: gate g[b,:] (tiny)
// ---------------------------------------------------------------------------
__global__ __launch_bounds__(192) void gate_kernel(
    const float* __restrict__ Fn, const float* __restrict__ Fr,
    const float* __restrict__ Wg, const float* __restrict__ bg,
    float* __restrict__ g_out)
{
    int b = blockIdx.x;
    int t = threadIdx.x;
    __shared__ float m[2 * D];

    if (t < 2 * D) {
        const float* src = (t < D) ? (Fn + (size_t)b * S * D + t)
                                   : (Fr + (size_t)b * S * D + (t - D));
        float s = 0.f;
        for (int r = 0; r < S; ++r) s += src[(size_t)r * D];
        m[t] = s * (1.0f / (float)S);
    }
    __syncthreads();
    if (t < D) {
        const float* w = Wg + (size_t)t * (2 * D);
        float a0 = 0.f, a1 = 0.f, a2 = 0.f, a3 = 0.f;
        int k = 0;
        for (; k + 3 < 2 * D; k += 4) {
            a0 += m[k] * w[k];         a1 += m[k + 1] * w[k + 1];
            a2 += m[k + 2] * w[k + 2]; a3 += m[k + 3] * w[k + 3];
        }
        for (; k < 2 * D; ++k) a0 += m[k] * w[k];
        float o = bg[t] + ((a0 + a1) + (a2 + a3));
        g_out[(size_t)b * D + t] = 1.0f / (1.0f + __expf(-o));
    }
}

// ---------------------------------------------------------------------------
// MFMA building blocks. Fragment maps (16x16x32):
//   A: lane holds A[l&15][8*(l>>4)+i]   -> row-major, 16B contiguous per lane
//   B: lane holds B[8*(l>>4)+i][l&15]   -> read Y row-major when computing X*Y^T
//   C/D: row=(l>>4)*4+r, col=l&15       [verified layout]
// ---------------------------------------------------------------------------

// Y[64x80] = X[64x96] * W^T (W row-major [80][104], rows>=65 zero) + bias; store bf16
__device__ __forceinline__ void proj16(const unsigned short (*X)[104],
                                       const unsigned short (*W)[104],
                                       const float* biasRow,
                                       unsigned short (*dst)[104],
                                       int mt, int lrow, int lgrp)
{
    f32x4 acc[5] = {};
    #pragma unroll
    for (int ks = 0; ks < 3; ++ks) {
        bf16x8 a = ldfrag(&X[mt * 16 + lrow][ks * 32 + lgrp * 8]);
        #pragma unroll
        for (int nt = 0; nt < 5; ++nt) {
            bf16x8 bfr = ldfrag(&W[nt * 16 + lrow][ks * 32 + lgrp * 8]);
            MFMA16(acc[nt], a, bfr);
        }
    }
    #pragma unroll
    for (int nt = 0; nt < 5; ++nt) {
        #pragma unroll
        for (int r = 0; r < 4; ++r) {
            int row = mt * 16 + lgrp * 4 + r;
            int col = nt * 16 + lrow;
            dst[row][col] = f2bf(acc[nt][r] + biasRow[col]);
        }
    }
}

// A[64x64] = rowsoftmax(mask(scale * Q*K^T)); store bf16 (cols>=62 masked to 0)
__device__ __forceinline__ void attn_softmax(const unsigned short (*Q)[104],
                                             const unsigned short (*K)[104],
                                             unsigned short (*A)[72],
                                             int mt, int lrow, int lgrp)
{
    const float scale = 0.12403473458920847f; // 1/sqrt(65)
    f32x4 acc[4] = {};
    #pragma unroll
    for (int ks = 0; ks < 3; ++ks) {
        bf16x8 a = ldfrag(&Q[mt * 16 + lrow][ks * 32 + lgrp * 8]);
        #pragma unroll
        for (int nt = 0; nt < 4; ++nt) {
            bf16x8 bfr = ldfrag(&K[nt * 16 + lrow][ks * 32 + lgrp * 8]);
            MFMA16(acc[nt], a, bfr);
        }
    }
    #pragma unroll
    for (int r = 0; r < 4; ++r) {
        float p[4];
        float mx = -1e30f;
        #pragma unroll
        for (int nt = 0; nt < 4; ++nt) {
            int col = nt * 16 + lrow;
            float v = (col < S) ? acc[nt][r] * scale : -1e30f;
            p[nt] = v;
            mx = fmaxf(mx, v);
        }
        mx = fmaxf(mx, __shfl_xor(mx, 1));
        mx = fmaxf(mx, __shfl_xor(mx, 2));
        mx = fmaxf(mx, __shfl_xor(mx, 4));
        mx = fmaxf(mx, __shfl_xor(mx, 8));
        float s = 0.f;
        #pragma unroll
        for (int nt = 0; nt < 4; ++nt) { float e = __expf(p[nt] - mx); p[nt] = e; s += e; }
        s += __shfl_xor(s, 1);
        s += __shfl_xor(s, 2);
        s += __shfl_xor(s, 4);
        s += __shfl_xor(s, 8);
        float inv = 1.0f / s;
        int row = mt * 16 + lgrp * 4 + r;
        #pragma unroll
        for (int nt = 0; nt < 4; ++nt)
            A[row][nt * 16 + lrow] = f2bf(p[nt] * inv);
    }
}

// out rows [rowOff..rowOff+61] = gate(col) * (A[64x64] @ V), V given transposed VT[dd][r]
__device__ __forceinline__ void av_out(const unsigned short (*A)[72],
                                       const unsigned short (*VT)[72],
                                       const float* sg, float* outp,
                                       int rowOff, int sideFlag,
                                       int mt, int lrow, int lgrp)
{
    f32x4 acc[5] = {};
    #pragma unroll
    for (int ks = 0; ks < 2; ++ks) {
        bf16x8 a = ldfrag(&A[mt * 16 + lrow][ks * 32 + lgrp * 8]);
        #pragma unroll
        for (int nt = 0; nt < 5; ++nt) {
            bf16x8 bfr = ldfrag(&VT[nt * 16 + lrow][ks * 32 + lgrp * 8]);
            MFMA16(acc[nt], a, bfr);
        }
    }
    #pragma unroll
    for (int nt = 0; nt < 5; ++nt) {
        #pragma unroll
        for (int r = 0; r < 4; ++r) {
            int row = mt * 16 + lgrp * 4 + r;
            int col = nt * 16 + lrow;
            if (row < S && col < D) {
                float gv = sideFlag ? (1.0f - sg[col]) : sg[col];
                outp[(size_t)(rowOff + row) * D + col] = gv * acc[nt][r];
            }
        }
    }
}

// ---------------------------------------------------------------------------
// Kernel 2: per-(b,h) fused dual attention, MFMA bf16
// ---------------------------------------------------------------------------
__global__ __launch_bounds__(NT) void attn_kernel(
    const float* __restrict__ Fn, const float* __restrict__ Fr,
    const float* __restrict__ Wq1, const float* __restrict__ bq1,
    const float* __restrict__ Wk1, const float* __restrict__ bk1,
    const float* __restrict__ Wq2, const float* __restrict__ bq2,
    const float* __restrict__ Wk2, const float* __restrict__ bk2,
    const float* __restrict__ g, float* __restrict__ out,
    float* __restrict__ orth_accum)
{
    __shared__ __align__(16) unsigned short sFn[64][104];
    __shared__ __align__(16) unsigned short sFr[64][104];
    __shared__ __align__(16) unsigned short sQ1[64][104];
    __shared__ __align__(16) unsigned short sK1[64][104];
    __shared__ __align__(16) unsigned short sQ2[64][104];
    __shared__ __align__(16) unsigned short sK2[64][104];
    __shared__ __align__(16) unsigned short sFnT[80][72];
    __shared__ __align__(16) unsigned short sFrT[80][72];
    __shared__ __align__(16) unsigned short sW0[80][104];
    __shared__ __align__(16) unsigned short sW1[80][104];
    __shared__ __align__(16) unsigned short sA1[64][72];
    __shared__ __align__(16) unsigned short sA2[64][72];
    __shared__ float sBias[4][80];
    __shared__ float sg[D];
    __shared__ float sred[8];

    const int blk  = blockIdx.x;
    const int b    = blk / H;
    const int h    = blk - b * H;
    const int tid  = threadIdx.x;
    const int wid  = tid >> 6;
    const int side = wid >> 2;      // 0: Q-side work, 1: K-side work
    const int mt   = wid & 3;       // M-tile (16 rows)
    const int lane = tid & 63;
    const int lrow = lane & 15;
    const int lgrp = lane >> 4;

    // ---- stage 0a: zero pads (uint4 stores) ----
    {
        const uint4 z = make_uint4(0, 0, 0, 0);
        uint4* bufs[10] = { (uint4*)&sFn[0][0], (uint4*)&sFr[0][0],
                            (uint4*)&sQ1[0][0], (uint4*)&sK1[0][0],
                            (uint4*)&sQ2[0][0], (uint4*)&sK2[0][0],
                            (uint4*)&sFnT[0][0], (uint4*)&sFrT[0][0],
                            (uint4*)&sW0[0][0], (uint4*)&sW1[0][0] };
        int len[10] = { 832, 832, 832, 832, 832, 832, 720, 720, 1040, 1040 };
        #pragma unroll
        for (int q = 0; q < 10; ++q)
            for (int i = tid; i < len[q]; i += NT) bufs[q][i] = z;
    }
    __syncthreads();

    // ---- stage 0b: fill Fn/Fr (+ transposes), W1-pair, biases, gate ----
    const size_t fb = (size_t)b * S * D;
    for (int idx = tid; idx < S * D; idx += NT) {
        int n = idx / D, d = idx - n * D;
        unsigned short bn = f2bf(Fn[fb + idx]);
        unsigned short br = f2bf(Fr[fb + idx]);
        sFn[n][d] = bn; sFr[n][d] = br;
        sFnT[d][n] = bn; sFrT[d][n] = br;
    }
    for (int idx = tid; idx < D * D; idx += NT) {
        int j = idx / D, d = idx - j * D;
        size_t o = (size_t)(h * D + j) * D + d;
        sW0[j][d] = f2bf(Wq1[o]);
        sW1[j][d] = f2bf(Wk1[o]);
    }
    for (int idx = tid; idx < 4 * 80; idx += NT) {
        int which = idx / 80, j = idx - which * 80;
        const float* bp = (which == 0) ? bq1 : (which == 1) ? bk1 : (which == 2) ? bq2 : bk2;
        sBias[which][j] = (j < D) ? bp[h * D + j] : 0.f;
    }
    for (int idx = tid; idx < D; idx += NT) sg[idx] = g[(size_t)b * D + idx];
    __syncthreads();

    // ---- P1: Q1 = Fn*Wq1^T (waves 0-3), K1 = Fr*Wk1^T (waves 4-7) ----
    if (side == 0) proj16(sFn, sW0, sBias[0], sQ1, mt, lrow, lgrp);
    else           proj16(sFr, sW1, sBias[1], sK1, mt, lrow, lgrp);
    __syncthreads();

    // ---- reload weights for attention 2 (pads still zero) ----
    for (int idx = tid; idx < D * D; idx += NT) {
        int j = idx / D, d = idx - j * D;
        size_t o = (size_t)(h * D + j) * D + d;
        sW0[j][d] = f2bf(Wq2[o]);
        sW1[j][d] = f2bf(Wk2[o]);
    }
    __syncthreads();

    // ---- P2: Q2 = Fr*Wq2^T, K2 = Fn*Wk2^T ----
    if (side == 0) proj16(sFr, sW0, sBias[2], sQ2, mt, lrow, lgrp);
    else           proj16(sFn, sW1, sBias[3], sK2, mt, lrow, lgrp);
    __syncthreads();

    // ---- S-stage: both attentions concurrently, in-register softmax ----
    if (side == 0) attn_softmax(sQ1, sK1, sA1, mt, lrow, lgrp);
    else           attn_softmax(sQ2, sK2, sA2, mt, lrow, lgrp);
    __syncthreads();

    // ---- C = A1*A2^T, orthogonality partial ----
    {
        f32x4 acc[2] = {};
        #pragma unroll
        for (int ks = 0; ks < 2; ++ks) {
            bf16x8 a = ldfrag(&sA1[mt * 16 + lrow][ks * 32 + lgrp * 8]);
            #pragma unroll
            for (int ntl = 0; ntl < 2; ++ntl) {
                bf16x8 bfr = ldfrag(&sA2[(side * 2 + ntl) * 16 + lrow][ks * 32 + lgrp * 8]);
                MFMA16(acc[ntl], a, bfr);
            }
        }
        float local = 0.f;
        #pragma unroll
        for (int ntl = 0; ntl < 2; ++ntl) {
            #pragma unroll
            for (int r = 0; r < 4; ++r) {
                int row = mt * 16 + lgrp * 4 + r;
                int col = (side * 2 + ntl) * 16 + lrow;
                if (row < S && col < S) {
                    float c = acc[ntl][r] - ((row == col) ? 1.0f : 0.0f);
                    local += c * c;
                }
            }
        }
        local += __shfl_xor(local, 1);
        local += __shfl_xor(local, 2);
        local += __shfl_xor(local, 4);
        local += __shfl_xor(local, 8);
        local += __shfl_xor(local, 16);
        local += __shfl_xor(local, 32);
        if (lane == 0) sred[wid] = local;
    }
    __syncthreads();
    if (tid == 0) {
        float tot = 0.f;
        #pragma unroll
        for (int wv = 0; wv < 8; ++wv) tot += sred[wv];
        atomicAdd(orth_accum, sqrtf(tot) * (1.0f / (float)(BS * H)));
    }

    // ---- AV + gated output ----
    float* outp = out + (size_t)blk * (2 * S * D);
    if (side == 0) av_out(sA1, sFrT, sg, outp, 0, 0, mt, lrow, lgrp);
    else           av_out(sA2, sFnT, sg, outp, S, 1, mt, lrow, lgrp);
}

// ---------------------------------------------------------------------------
extern "C" void kernel_launch(void* const* d_in, const int* in_sizes, int n_in,
                              void* d_out, int out_size, void* d_ws, size_t ws_size,
                              hipStream_t stream)
{
    const float* Fn  = (const float*)d_in[0];
    const float* Fr  = (const float*)d_in[1];
    const float* Wq1 = (const float*)d_in[2];
    const float* bq1 = (const float*)d_in[3];
    const float* Wk1 = (const float*)d_in[4];
    const float* bk1 = (const float*)d_in[5];
    const float* Wq2 = (const float*)d_in[6];
    const float* bq2 = (const float*)d_in[7];
    const float* Wk2 = (const float*)d_in[8];
    const float* bk2 = (const float*)d_in[9];
    const float* Wg  = (const float*)d_in[10];
    const float* bg  = (const float*)d_in[11];

    float* out  = (float*)d_out;
    float* g_ws = (float*)d_ws;   // 1024*65 floats

    hipMemsetAsync(out + FUSED_SIZE, 0, sizeof(float), stream);

    gate_kernel<<<BS, 192, 0, stream>>>(Fn, Fr, Wg, bg, g_ws);
    attn_kernel<<<BS * H, NT, 0, stream>>>(Fn, Fr, Wq1, bq1, Wk1, bk1,
                                           Wq2, bq2, Wk2, bk2,
                                           g_ws, out, out + FUSED_SIZE);
}